// Round 7
// baseline (7358.412 us; speedup 1.0000x reference)
//
#include <hip/hip_runtime.h>
#include <math.h>

// GPT forward: B=2, T=2048, C=768, H=12, hd=64, L=4, V=50257
// out = logits[B*T*V] (fp32) then loss[1] (fp32), concatenated.
// GEMMs run as bf16x3 split-MFMA (error ~2^-16 per product, fp32-equivalent).
// Staging via global_load_lds (16B) into XOR-swizzled linear LDS (rule #21:
// linear dest + inverse-swizzled global source + swizzled ds_read).
// Block-to-tile mapping uses the bijective XCD swizzle (m204).

#define TT 2048
#define CC 768
#define HH 12
#define HD 64
#define VV 50257
#define BBATCH 2
#define ROWS (BBATCH * TT) /* 4096 */
#define LMSTRIP 8192

typedef __attribute__((ext_vector_type(8))) short short8;   // 8 bf16 (4 VGPR)
typedef __attribute__((ext_vector_type(4))) float floatx4;  // MFMA acc

// address-space-qualified pointer types for the global_load_lds builtin
// (prototype is v*1 / v*3; generic pointers do NOT implicitly convert).
typedef const void __attribute__((address_space(1)))* gas1_cvp;
typedef void __attribute__((address_space(3)))* as3_vp;

// CK-style cast chain: generic -> integer -> AS pointer. Low 32 bits of a
// generic LDS address are the AS3 offset (that is how addrspacecast lowers).
static __device__ __forceinline__ void gload_lds16(const void* g, void* l) {
  __builtin_amdgcn_global_load_lds(
      (gas1_cvp)(unsigned long long)g,
      (as3_vp)(unsigned int)(unsigned long long)l, 16, 0, 0);
}

static __device__ __forceinline__ ushort f2bf(float x) {
  unsigned u = __float_as_uint(x);
  unsigned r = (u + 0x7fff + ((u >> 16) & 1)) >> 16;  // round-nearest-even
  return (ushort)r;
}
static __device__ __forceinline__ float bf2f(ushort h) {
  return __uint_as_float(((unsigned)h) << 16);
}

// Bijective XCD-aware remap (m204): blocks sharing orig%8 (same XCD under
// round-robin dispatch) receive a contiguous chunk of linear tile ids.
static __device__ __forceinline__ void xcd_swizzle(int gx, int gy, int& bx, int& by) {
  int nwg = gx * gy;
  int orig = by * gx + bx;
  int q = nwg >> 3, r = nwg & 7;
  int xcd = orig & 7, local = orig >> 3;
  int wgid = (xcd < r ? xcd * (q + 1) : r * (q + 1) + (xcd - r) * q) + local;
  bx = wgid % gx;
  by = wgid / gx;
}

// ---------------------------------------------------------------- embedding
__global__ void embed_kernel(const int* __restrict__ idx,
                             const float* __restrict__ wte,
                             const float* __restrict__ wpe,
                             float* __restrict__ x) {
  int i = blockIdx.x * blockDim.x + threadIdx.x; // float4 index
  int row = i / (CC / 4);
  int c4 = (i % (CC / 4)) * 4;
  int t = row % TT;
  int tok = idx[row];
  float4 a = *(const float4*)(wte + (size_t)tok * CC + c4);
  float4 p = *(const float4*)(wpe + (size_t)t * CC + c4);
  float4 o;
  o.x = a.x + p.x; o.y = a.y + p.y; o.z = a.z + p.z; o.w = a.w + p.w;
  *(float4*)(x + (size_t)row * CC + c4) = o;
}

// ------------------------------------------------- layernorm -> bf16 hi/lo
// one wave per row (C=768 -> 12 floats/lane), block = 4 waves
__global__ void ln_split_kernel(const float* __restrict__ x,
                                const float* __restrict__ w,
                                ushort* __restrict__ hhi,
                                ushort* __restrict__ hlo) {
  int wid = threadIdx.x >> 6;
  int lane = threadIdx.x & 63;
  int row = blockIdx.x * 4 + wid;
  const float* xr = x + (size_t)row * CC;
  float v[12];
#pragma unroll
  for (int c = 0; c < 3; c++) {
    float4 t = *(const float4*)(xr + c * 256 + lane * 4);
    v[c * 4 + 0] = t.x; v[c * 4 + 1] = t.y; v[c * 4 + 2] = t.z; v[c * 4 + 3] = t.w;
  }
  float s = 0.f;
#pragma unroll
  for (int i = 0; i < 12; i++) s += v[i];
#pragma unroll
  for (int o = 32; o > 0; o >>= 1) s += __shfl_xor(s, o);
  float mean = s * (1.0f / CC);
  float vs = 0.f;
#pragma unroll
  for (int i = 0; i < 12; i++) { float d = v[i] - mean; vs += d * d; }
#pragma unroll
  for (int o = 32; o > 0; o >>= 1) vs += __shfl_xor(vs, o);
  float rs = rsqrtf(vs * (1.0f / CC) + 1e-5f);
#pragma unroll
  for (int c = 0; c < 3; c++) {
    float4 wv = *(const float4*)(w + c * 256 + lane * 4);
    float r[4];
    r[0] = (v[c * 4 + 0] - mean) * rs * wv.x;
    r[1] = (v[c * 4 + 1] - mean) * rs * wv.y;
    r[2] = (v[c * 4 + 2] - mean) * rs * wv.z;
    r[3] = (v[c * 4 + 3] - mean) * rs * wv.w;
    ushort4 h, l;
    h.x = f2bf(r[0]); l.x = f2bf(r[0] - bf2f(h.x));
    h.y = f2bf(r[1]); l.y = f2bf(r[1] - bf2f(h.y));
    h.z = f2bf(r[2]); l.z = f2bf(r[2] - bf2f(h.z));
    h.w = f2bf(r[3]); l.w = f2bf(r[3] - bf2f(h.w));
    size_t ob = (size_t)row * CC + c * 256 + lane * 4;
    *(ushort4*)(hhi + ob) = h;
    *(ushort4*)(hlo + ob) = l;
  }
}

// --------------------------------------- weight transpose + bf16 hi/lo split
// in: [Ktot][Ntot] fp32 (row stride Ntot), cols [c0, c0+gridDim.x*32)
// out: [n - c0][Ktot] bf16 hi/lo (row stride Ktot); zero-fill for n >= Ntot
__global__ void convt_kernel(const float* __restrict__ in, int Ktot, int Ntot,
                             int c0, ushort* __restrict__ oh,
                             ushort* __restrict__ ol) {
  __shared__ float T[32][33];
  const int n0 = blockIdx.x * 32, k0 = blockIdx.y * 32;
  const int tid = threadIdx.x;
  {
    const int kr = tid >> 3, nc = (tid & 7) * 4;
#pragma unroll
    for (int i = 0; i < 4; i++) {
      int gc = c0 + n0 + nc + i;
      float v = 0.f;
      if (gc < Ntot) v = in[(size_t)(k0 + kr) * Ntot + gc];
      T[kr][nc + i] = v;
    }
  }
  __syncthreads();
  const int nr = tid >> 3, kc = (tid & 7) * 4;
  ushort4 h, l;
  float v0 = T[kc + 0][nr], v1 = T[kc + 1][nr], v2 = T[kc + 2][nr], v3 = T[kc + 3][nr];
  h.x = f2bf(v0); l.x = f2bf(v0 - bf2f(h.x));
  h.y = f2bf(v1); l.y = f2bf(v1 - bf2f(h.y));
  h.z = f2bf(v2); l.z = f2bf(v2 - bf2f(h.z));
  h.w = f2bf(v3); l.w = f2bf(v3 - bf2f(h.w));
  size_t ob = (size_t)(n0 + nr) * Ktot + k0 + kc;
  *(ushort4*)(oh + ob) = h;
  *(ushort4*)(ol + ob) = l;
}

// ------------------------------------------------------------ bf16x3 GEMM
// C[M,N] = A[M,K] @ B[K,N]; A given as hi/lo [M][K], B as hi/lo [N][K]
// (pre-transposed). 128x128 tile, BK=32, 4 waves, 64x64 per wave (4x4 frags
// of mfma_f32_16x16x32_bf16). Staging: each wave DMA's its own plane via
// global_load_lds (8 issues x 1KB), double-buffered, one barrier per K-step.
// LDS plane [128][32] ushort linear; 16B-slot swizzle s = g ^ ((row>>1)&3)
// makes both DMA writes (contiguous) and frag ds_read_b128 conflict-free.
// EPI: 0=none 1=+res 2=gelu. NGUARD: col<nvalid. OSPLIT: write bf16 hi/lo.
template <int EPI, bool NGUARD, bool OSPLIT>
__global__ __launch_bounds__(256, 2) void gemm_bf16x3(
    const ushort* __restrict__ Ah, const ushort* __restrict__ Al,
    const ushort* __restrict__ Bh, const ushort* __restrict__ Bl,
    const float* __restrict__ Res, float* __restrict__ C,
    ushort* __restrict__ Oh, ushort* __restrict__ Ol,
    int K, int ldc, int nvalid) {
  __shared__ ushort S[2][4][128][32];  // [buf][plane: Ah,Al,Bh,Bl][row][k]
  const int tid = threadIdx.x;
  int bx = blockIdx.x, by = blockIdx.y;
  xcd_swizzle(gridDim.x, gridDim.y, bx, by);
  const int m0 = by * 128;
  const int n0 = bx * 128;
  const int lane = tid & 63;
  const int wid = tid >> 6;
  const int wr = wid >> 1, wc = wid & 1;  // wave 2x2 grid of 64x64
  const int fr = lane & 15, fq = lane >> 4;

  // staging geometry: wave `wid` owns plane `wid`; issue i covers rows
  // i*16..i*16+15; lane l -> physical (row = i*16 + (l>>2), slot = l&3),
  // fetching global k-group g = slot ^ ((row>>1)&3)  (XOR involution).
  const ushort* gplane = (wid == 0) ? Ah : (wid == 1) ? Al : (wid == 2) ? Bh : Bl;
  const int t0 = (wid < 2) ? m0 : n0;
  const int srow = lane >> 2;
  const int sslot = lane & 3;

  floatx4 acc[4][4] = {};

  auto stage = [&](int buf, int kk) {
#pragma unroll
    for (int i = 0; i < 8; i++) {
      int r = i * 16 + srow;
      int g = sslot ^ ((r >> 1) & 3);
      const ushort* gp = gplane + (size_t)(t0 + r) * K + kk + g * 8;
      gload_lds16((const void*)gp, (void*)&S[buf][wid][i * 16][0]);
    }
  };

  stage(0, 0);
  int cur = 0;
  for (int k0 = 0; k0 < K; k0 += 32) {
    // drains vmcnt (DMA into buf[cur] done) + lgkm (prev reads done)
    __syncthreads();
    if (k0 + 32 < K) stage(cur ^ 1, k0 + 32);  // next tile in flight over MFMA

    short8 fah[4], fal[4], fbh[4], fbl[4];
#pragma unroll
    for (int mi = 0; mi < 4; mi++) {
      int R = wr * 64 + mi * 16 + fr;
      int sw = (fq ^ ((R >> 1) & 3)) * 8;
      fah[mi] = *reinterpret_cast<const short8*>(&S[cur][0][R][sw]);
      fal[mi] = *reinterpret_cast<const short8*>(&S[cur][1][R][sw]);
    }
#pragma unroll
    for (int ni = 0; ni < 4; ni++) {
      int R = wc * 64 + ni * 16 + fr;
      int sw = (fq ^ ((R >> 1) & 3)) * 8;
      fbh[ni] = *reinterpret_cast<const short8*>(&S[cur][2][R][sw]);
      fbl[ni] = *reinterpret_cast<const short8*>(&S[cur][3][R][sw]);
    }
#pragma unroll
    for (int mi = 0; mi < 4; mi++)
#pragma unroll
      for (int ni = 0; ni < 4; ni++) {
        acc[mi][ni] = __builtin_amdgcn_mfma_f32_16x16x32_bf16(fah[mi], fbh[ni], acc[mi][ni], 0, 0, 0);
        acc[mi][ni] = __builtin_amdgcn_mfma_f32_16x16x32_bf16(fah[mi], fbl[ni], acc[mi][ni], 0, 0, 0);
        acc[mi][ni] = __builtin_amdgcn_mfma_f32_16x16x32_bf16(fal[mi], fbh[ni], acc[mi][ni], 0, 0, 0);
      }
    cur ^= 1;
  }

#pragma unroll
  for (int mi = 0; mi < 4; mi++) {
#pragma unroll
    for (int ni = 0; ni < 4; ni++) {
      int col = n0 + wc * 64 + ni * 16 + fr;
      if (!NGUARD || col < nvalid) {
#pragma unroll
        for (int j = 0; j < 4; j++) {
          int row = m0 + wr * 64 + mi * 16 + fq * 4 + j;
          float v = acc[mi][ni][j];
          if (EPI == 1) v += Res[(size_t)row * ldc + col];
          if (EPI == 2) v = 0.5f * v * (1.0f + erff(v * 0.70710678118654752f));
          if (OSPLIT) {
            ushort hi = f2bf(v);
            ushort lo = f2bf(v - bf2f(hi));
            Oh[(size_t)row * ldc + col] = hi;
            Ol[(size_t)row * ldc + col] = lo;
          } else {
            C[(size_t)row * ldc + col] = v;
          }
        }
      }
    }
  }
}

// ---------------------------------------------------------------- attention
// 1 thread = 1 query row (q,o in regs). 32x64 K/V tiles in LDS, broadcast
// reads. Online softmax fully per-thread (defer-rescale + whole-masked-tile
// skip: fully masked tiles contribute exactly 0). Block = 256 q rows.
// Output written directly as bf16 hi/lo planes (feeds proj GEMM A-operand).
__global__ __launch_bounds__(256) void attn_kernel(const float* __restrict__ qkv,
                                                   ushort* __restrict__ yh,
                                                   ushort* __restrict__ yl) {
  __shared__ float Ks[32][64];
  __shared__ float Vs[32][64];
  const int tid = threadIdx.x;
  const int bh = blockIdx.y;
  const int b = bh / HH, h = bh % HH;
  const int q0 = blockIdx.x * 256;
  const int qi = q0 + tid;
  const float* qptr = qkv + ((size_t)(b * TT + qi)) * (3 * CC) + h * HD;
  float q[HD], o[HD];
#pragma unroll
  for (int i = 0; i < HD / 4; i++) {
    float4 t = *(const float4*)(qptr + i * 4);
    q[i * 4] = t.x; q[i * 4 + 1] = t.y; q[i * 4 + 2] = t.z; q[i * 4 + 3] = t.w;
  }
#pragma unroll
  for (int i = 0; i < HD; i++) o[i] = 0.f;
  float m = -INFINITY, l = 0.f;

  const int kr = tid >> 3;       // tile row 0..31
  const int kc = (tid & 7) * 8;  // col base
  const size_t kbase = ((size_t)b * TT) * (3 * CC) + CC + h * HD;
  const size_t vbase = kbase + CC;

  for (int ks = 0; ks <= q0 + 255; ks += 32) {
    {
      const float* kp = qkv + kbase + (size_t)(ks + kr) * (3 * CC) + kc;
      float4 t0 = *(const float4*)(kp);
      float4 t1 = *(const float4*)(kp + 4);
      *(float4*)&Ks[kr][kc] = t0;
      *(float4*)&Ks[kr][kc + 4] = t1;
      const float* vp = qkv + vbase + (size_t)(ks + kr) * (3 * CC) + kc;
      float4 t2 = *(const float4*)(vp);
      float4 t3 = *(const float4*)(vp + 4);
      *(float4*)&Vs[kr][kc] = t2;
      *(float4*)&Vs[kr][kc + 4] = t3;
    }
    __syncthreads();
    float s[32];
    float tmax = -INFINITY;
#pragma unroll
    for (int j = 0; j < 32; j++) {
      float acc = 0.f;
#pragma unroll
      for (int d = 0; d < HD; d += 4) {
        float4 kv = *(const float4*)&Ks[j][d];
        acc = fmaf(q[d + 0], kv.x, acc);
        acc = fmaf(q[d + 1], kv.y, acc);
        acc = fmaf(q[d + 2], kv.z, acc);
        acc = fmaf(q[d + 3], kv.w, acc);
      }
      acc *= 0.125f; // 1/sqrt(64)
      if (ks + j > qi) acc = -INFINITY;
      s[j] = acc;
      tmax = fmaxf(tmax, acc);
    }
    if (tmax != -INFINITY) {  // tile has >=1 valid key for this thread
      if (tmax > m) {         // running max grew (always true on first tile)
        float f = __expf(m - tmax);  // exp(-inf)=0 on first tile
        l *= f;
#pragma unroll
        for (int d = 0; d < HD; d++) o[d] *= f;
        m = tmax;
      }
      float ps = 0.f;
#pragma unroll
      for (int j = 0; j < 32; j++) {
        float p = __expf(s[j] - m);
        s[j] = p;
        ps += p;
      }
      l += ps;
#pragma unroll
      for (int j = 0; j < 32; j++) {
        float p = s[j];
#pragma unroll
        for (int d = 0; d < HD; d += 4) {
          float4 vv = *(const float4*)&Vs[j][d];
          o[d + 0] = fmaf(p, vv.x, o[d + 0]);
          o[d + 1] = fmaf(p, vv.y, o[d + 1]);
          o[d + 2] = fmaf(p, vv.z, o[d + 2]);
          o[d + 3] = fmaf(p, vv.w, o[d + 3]);
        }
      }
    }
    __syncthreads();
  }
  float inv = 1.0f / l;
  size_t yoff = ((size_t)(b * TT + qi)) * CC + h * HD;
#pragma unroll
  for (int d = 0; d < HD; d += 4) {
    ushort4 hv, lv;
    float r0 = o[d + 0] * inv, r1 = o[d + 1] * inv;
    float r2 = o[d + 2] * inv, r3 = o[d + 3] * inv;
    hv.x = f2bf(r0); lv.x = f2bf(r0 - bf2f(hv.x));
    hv.y = f2bf(r1); lv.y = f2bf(r1 - bf2f(hv.y));
    hv.z = f2bf(r2); lv.z = f2bf(r2 - bf2f(hv.z));
    hv.w = f2bf(r3); lv.w = f2bf(r3 - bf2f(hv.w));
    *(ushort4*)(yh + yoff + d) = hv;
    *(ushort4*)(yl + yoff + d) = lv;
  }
}

// ------------------------------------------------- loss (single-pass online)
__global__ void loss_rows_kernel(const float* __restrict__ logits,
                                 const int* __restrict__ tgt,
                                 float* __restrict__ rloss) {
  __shared__ float redm[4], reds[4];
  const int row = blockIdx.x;
  const int tid = threadIdx.x;
  const int wid = tid >> 6, lane = tid & 63;
  const float* lr = logits + (size_t)row * VV;
  float m = -INFINITY, s = 0.f;
  // 12564 float4 groups cover elements [0, 50256); element 50256 is the tail.
  for (int i = tid; i < 12564; i += 256) {
    float4 v = *(const float4*)(lr + 4 * i);
    float mv = fmaxf(fmaxf(v.x, v.y), fmaxf(v.z, v.w));
    float mn = fmaxf(m, mv);
    s = s * __expf(m - mn) + __expf(v.x - mn) + __expf(v.y - mn) +
        __expf(v.z - mn) + __expf(v.w - mn);
    m = mn;
  }
  if (tid == 0) {
    float v = lr[VV - 1];
    float mn = fmaxf(m, v);
    s = s * __expf(m - mn) + __expf(v - mn);
    m = mn;
  }
#pragma unroll
  for (int o = 32; o > 0; o >>= 1) {
    float mo = __shfl_xor(m, o), so = __shfl_xor(s, o);
    float mn = fmaxf(m, mo);
    s = s * __expf(m - mn) + so * __expf(mo - mn);
    m = mn;
  }
  if (lane == 0) { redm[wid] = m; reds[wid] = s; }
  __syncthreads();
  if (tid == 0) {
    float M = redm[0], S = reds[0];
#pragma unroll
    for (int w = 1; w < 4; w++) {
      float mn = fmaxf(M, redm[w]);
      S = S * __expf(M - mn) + reds[w] * __expf(redm[w] - mn);
      M = mn;
    }
    float lt = lr[tgt[row]];
    rloss[row] = -(lt - M - logf(S));
  }
}

__global__ void loss_final_kernel(const float* __restrict__ rloss,
                                  float* __restrict__ out) {
  __shared__ float red[4];
  const int tid = threadIdx.x;
  const int wid = tid >> 6, lane = tid & 63;
  float s = 0.f;
  for (int i = tid; i < ROWS; i += 256) s += rloss[i];
#pragma unroll
  for (int o = 32; o > 0; o >>= 1) s += __shfl_xor(s, o);
  if (lane == 0) red[wid] = s;
  __syncthreads();
  if (tid == 0) out[0] = (red[0] + red[1] + red[2] + red[3]) * (1.0f / ROWS);
}

// ---------------------------------------------------------------- launch
extern "C" void kernel_launch(void* const* d_in, const int* in_sizes, int n_in,
                              void* d_out, int out_size, void* d_ws, size_t ws_size,
                              hipStream_t stream) {
  const int* idx = (const int*)d_in[0];
  const int* tgt = (const int*)d_in[1];
  const float* wte = (const float*)d_in[2];
  const float* wpe = (const float*)d_in[3];
  const float* ln1w = (const float*)d_in[4];
  const float* attnw = (const float*)d_in[5];
  const float* attnpw = (const float*)d_in[6];
  const float* ln2w = (const float*)d_in[7];
  const float* fcw = (const float*)d_in[8];
  const float* mlppw = (const float*)d_in[9];
  const float* lnfw = (const float*)d_in[10];
  const float* lmw = (const float*)d_in[11];

  float* logits = (float*)d_out;
  float* loss = logits + (size_t)ROWS * VV;

  // ---- workspace carve-up (~139 MB) ----
  float* x = (float*)d_ws;                        // [4096][768] fp32 residual
  float* qkvb = x + (size_t)ROWS * CC;            // [4096][2304] fp32
  float* rls = qkvb + (size_t)ROWS * 3 * CC;      // [4096]
  ushort* h_hi = (ushort*)(rls + ROWS);           // [4096][768] bf16 (ln out / attn out)
  ushort* h_lo = h_hi + (size_t)ROWS * CC;
  ushort* fA_hi = h_lo + (size_t)ROWS * CC;       // [4096][3072] bf16 (fc out)
  ushort* fA_lo = fA_hi + (size_t)ROWS * 4 * CC;
  ushort* wb_hi = fA_lo + (size_t)ROWS * 4 * CC;  // weight-T planes [8192][768] max
  ushort* wb_lo = wb_hi + (size_t)LMSTRIP * CC;

  embed_kernel<<<ROWS * CC / 4 / 256, 256, 0, stream>>>(idx, wte, wpe, x);

  for (int l = 0; l < 4; l++) {
    // --- attention half ---
    ln_split_kernel<<<ROWS / 4, 256, 0, stream>>>(x, ln1w + (size_t)l * CC, h_hi, h_lo);
    convt_kernel<<<dim3(3 * CC / 32, CC / 32), 256, 0, stream>>>(
        attnw + (size_t)l * CC * 3 * CC, CC, 3 * CC, 0, wb_hi, wb_lo);
    gemm_bf16x3<0, false, false><<<dim3(3 * CC / 128, ROWS / 128), 256, 0, stream>>>(
        h_hi, h_lo, wb_hi, wb_lo, nullptr, qkvb, nullptr, nullptr, CC, 3 * CC, 3 * CC);
    attn_kernel<<<dim3(TT / 256, BBATCH * HH), 256, 0, stream>>>(qkvb, h_hi, h_lo);
    convt_kernel<<<dim3(CC / 32, CC / 32), 256, 0, stream>>>(
        attnpw + (size_t)l * CC * CC, CC, CC, 0, wb_hi, wb_lo);
    gemm_bf16x3<1, false, false><<<dim3(CC / 128, ROWS / 128), 256, 0, stream>>>(
        h_hi, h_lo, wb_hi, wb_lo, x, x, nullptr, nullptr, CC, CC, CC);
    // --- MLP half ---
    ln_split_kernel<<<ROWS / 4, 256, 0, stream>>>(x, ln2w + (size_t)l * CC, h_hi, h_lo);
    convt_kernel<<<dim3(4 * CC / 32, CC / 32), 256, 0, stream>>>(
        fcw + (size_t)l * CC * 4 * CC, CC, 4 * CC, 0, wb_hi, wb_lo);
    gemm_bf16x3<2, false, true><<<dim3(4 * CC / 128, ROWS / 128), 256, 0, stream>>>(
        h_hi, h_lo, wb_hi, wb_lo, nullptr, nullptr, fA_hi, fA_lo, CC, 4 * CC, 4 * CC);
    convt_kernel<<<dim3(CC / 32, 4 * CC / 32), 256, 0, stream>>>(
        mlppw + (size_t)l * 4 * CC * CC, 4 * CC, CC, 0, wb_hi, wb_lo);
    gemm_bf16x3<1, false, false><<<dim3(CC / 128, ROWS / 128), 256, 0, stream>>>(
        fA_hi, fA_lo, wb_hi, wb_lo, x, x, nullptr, nullptr, 4 * CC, CC, CC);
  }

  ln_split_kernel<<<ROWS / 4, 256, 0, stream>>>(x, lnfw, h_hi, h_lo);

  // lm_head in column strips of 8192 through the weight-T buffer
  for (int c0 = 0; c0 < VV; c0 += LMSTRIP) {
    int nt = VV - c0 < LMSTRIP ? VV - c0 : LMSTRIP;
    convt_kernel<<<dim3(LMSTRIP / 32, CC / 32), 256, 0, stream>>>(
        lmw, CC, VV, c0, wb_hi, wb_lo);
    if (nt == LMSTRIP) {
      gemm_bf16x3<0, false, false><<<dim3(LMSTRIP / 128, ROWS / 128), 256, 0, stream>>>(
          h_hi, h_lo, wb_hi, wb_lo, nullptr, logits + c0, nullptr, nullptr, CC, VV, nt);
    } else {
      gemm_bf16x3<0, true, false><<<dim3((nt + 127) / 128, ROWS / 128), 256, 0, stream>>>(
          h_hi, h_lo, wb_hi, wb_lo, nullptr, logits + c0, nullptr, nullptr, CC, VV, nt);
    }
  }

  loss_rows_kernel<<<ROWS, 256, 0, stream>>>(logits, tgt, rls);
  loss_final_kernel<<<1, 256, 0, stream>>>(rls, loss);
}

// Round 8
// 5706.300 us; speedup vs baseline: 1.2895x; 1.2895x over previous
//
#include <hip/hip_runtime.h>
#include <math.h>

// GPT forward: B=2, T=2048, C=768, H=12, hd=64, L=4, V=50257
// out = logits[B*T*V] (fp32) then loss[1] (fp32), concatenated.
// GEMMs run as bf16x3 split-MFMA (error ~2^-16 per product, fp32-equivalent).
// Staging via global_load_lds (16B) into XOR-swizzled linear LDS (rule #21:
// linear dest + inverse-swizzled global source + swizzled ds_read).
// Block-to-tile mapping uses the bijective XCD swizzle (m204).
// Attention: 4 lanes per q-row (R7 counters: 1-thread-per-row was
// occupancy-bound at 4.8%, VALUBusy 15%).

#define TT 2048
#define CC 768
#define HH 12
#define HD 64
#define VV 50257
#define BBATCH 2
#define ROWS (BBATCH * TT) /* 4096 */
#define LMSTRIP 8192

typedef __attribute__((ext_vector_type(8))) short short8;   // 8 bf16 (4 VGPR)
typedef __attribute__((ext_vector_type(4))) float floatx4;  // MFMA acc

// address-space-qualified pointer types for the global_load_lds builtin
// (prototype is v*1 / v*3; generic pointers do NOT implicitly convert).
typedef const void __attribute__((address_space(1)))* gas1_cvp;
typedef void __attribute__((address_space(3)))* as3_vp;

// CK-style cast chain: generic -> integer -> AS pointer. Low 32 bits of a
// generic LDS address are the AS3 offset (that is how addrspacecast lowers).
static __device__ __forceinline__ void gload_lds16(const void* g, void* l) {
  __builtin_amdgcn_global_load_lds(
      (gas1_cvp)(unsigned long long)g,
      (as3_vp)(unsigned int)(unsigned long long)l, 16, 0, 0);
}

static __device__ __forceinline__ ushort f2bf(float x) {
  unsigned u = __float_as_uint(x);
  unsigned r = (u + 0x7fff + ((u >> 16) & 1)) >> 16;  // round-nearest-even
  return (ushort)r;
}
static __device__ __forceinline__ float bf2f(ushort h) {
  return __uint_as_float(((unsigned)h) << 16);
}

// Bijective XCD-aware remap (m204): blocks sharing orig%8 (same XCD under
// round-robin dispatch) receive a contiguous chunk of linear tile ids.
static __device__ __forceinline__ void xcd_swizzle(int gx, int gy, int& bx, int& by) {
  int nwg = gx * gy;
  int orig = by * gx + bx;
  int q = nwg >> 3, r = nwg & 7;
  int xcd = orig & 7, local = orig >> 3;
  int wgid = (xcd < r ? xcd * (q + 1) : r * (q + 1) + (xcd - r) * q) + local;
  bx = wgid % gx;
  by = wgid / gx;
}

// ---------------------------------------------------------------- embedding
__global__ void embed_kernel(const int* __restrict__ idx,
                             const float* __restrict__ wte,
                             const float* __restrict__ wpe,
                             float* __restrict__ x) {
  int i = blockIdx.x * blockDim.x + threadIdx.x; // float4 index
  int row = i / (CC / 4);
  int c4 = (i % (CC / 4)) * 4;
  int t = row % TT;
  int tok = idx[row];
  float4 a = *(const float4*)(wte + (size_t)tok * CC + c4);
  float4 p = *(const float4*)(wpe + (size_t)t * CC + c4);
  float4 o;
  o.x = a.x + p.x; o.y = a.y + p.y; o.z = a.z + p.z; o.w = a.w + p.w;
  *(float4*)(x + (size_t)row * CC + c4) = o;
}

// ------------------------------------------------- layernorm -> bf16 hi/lo
// one wave per row (C=768 -> 12 floats/lane), block = 4 waves
__global__ void ln_split_kernel(const float* __restrict__ x,
                                const float* __restrict__ w,
                                ushort* __restrict__ hhi,
                                ushort* __restrict__ hlo) {
  int wid = threadIdx.x >> 6;
  int lane = threadIdx.x & 63;
  int row = blockIdx.x * 4 + wid;
  const float* xr = x + (size_t)row * CC;
  float v[12];
#pragma unroll
  for (int c = 0; c < 3; c++) {
    float4 t = *(const float4*)(xr + c * 256 + lane * 4);
    v[c * 4 + 0] = t.x; v[c * 4 + 1] = t.y; v[c * 4 + 2] = t.z; v[c * 4 + 3] = t.w;
  }
  float s = 0.f;
#pragma unroll
  for (int i = 0; i < 12; i++) s += v[i];
#pragma unroll
  for (int o = 32; o > 0; o >>= 1) s += __shfl_xor(s, o);
  float mean = s * (1.0f / CC);
  float vs = 0.f;
#pragma unroll
  for (int i = 0; i < 12; i++) { float d = v[i] - mean; vs += d * d; }
#pragma unroll
  for (int o = 32; o > 0; o >>= 1) vs += __shfl_xor(vs, o);
  float rs = rsqrtf(vs * (1.0f / CC) + 1e-5f);
#pragma unroll
  for (int c = 0; c < 3; c++) {
    float4 wv = *(const float4*)(w + c * 256 + lane * 4);
    float r[4];
    r[0] = (v[c * 4 + 0] - mean) * rs * wv.x;
    r[1] = (v[c * 4 + 1] - mean) * rs * wv.y;
    r[2] = (v[c * 4 + 2] - mean) * rs * wv.z;
    r[3] = (v[c * 4 + 3] - mean) * rs * wv.w;
    ushort4 h, l;
    h.x = f2bf(r[0]); l.x = f2bf(r[0] - bf2f(h.x));
    h.y = f2bf(r[1]); l.y = f2bf(r[1] - bf2f(h.y));
    h.z = f2bf(r[2]); l.z = f2bf(r[2] - bf2f(h.z));
    h.w = f2bf(r[3]); l.w = f2bf(r[3] - bf2f(h.w));
    size_t ob = (size_t)row * CC + c * 256 + lane * 4;
    *(ushort4*)(hhi + ob) = h;
    *(ushort4*)(hlo + ob) = l;
  }
}

// --------------------------------------- weight transpose + bf16 hi/lo split
// in: [Ktot][Ntot] fp32 (row stride Ntot), cols [c0, c0+gridDim.x*32)
// out: [n - c0][Ktot] bf16 hi/lo (row stride Ktot); zero-fill for n >= Ntot
__global__ void convt_kernel(const float* __restrict__ in, int Ktot, int Ntot,
                             int c0, ushort* __restrict__ oh,
                             ushort* __restrict__ ol) {
  __shared__ float T[32][33];
  const int n0 = blockIdx.x * 32, k0 = blockIdx.y * 32;
  const int tid = threadIdx.x;
  {
    const int kr = tid >> 3, nc = (tid & 7) * 4;
#pragma unroll
    for (int i = 0; i < 4; i++) {
      int gc = c0 + n0 + nc + i;
      float v = 0.f;
      if (gc < Ntot) v = in[(size_t)(k0 + kr) * Ntot + gc];
      T[kr][nc + i] = v;
    }
  }
  __syncthreads();
  const int nr = tid >> 3, kc = (tid & 7) * 4;
  ushort4 h, l;
  float v0 = T[kc + 0][nr], v1 = T[kc + 1][nr], v2 = T[kc + 2][nr], v3 = T[kc + 3][nr];
  h.x = f2bf(v0); l.x = f2bf(v0 - bf2f(h.x));
  h.y = f2bf(v1); l.y = f2bf(v1 - bf2f(h.y));
  h.z = f2bf(v2); l.z = f2bf(v2 - bf2f(h.z));
  h.w = f2bf(v3); l.w = f2bf(v3 - bf2f(h.w));
  size_t ob = (size_t)(n0 + nr) * Ktot + k0 + kc;
  *(ushort4*)(oh + ob) = h;
  *(ushort4*)(ol + ob) = l;
}

// ------------------------------------------------------------ bf16x3 GEMM
// C[M,N] = A[M,K] @ B[K,N]; A given as hi/lo [M][K], B as hi/lo [N][K]
// (pre-transposed). 128x128 tile, BK=32, 4 waves, 64x64 per wave (4x4 frags
// of mfma_f32_16x16x32_bf16). Staging: each wave DMA's its own plane via
// global_load_lds (8 issues x 1KB), double-buffered, one barrier per K-step.
// LDS plane [128][32] ushort linear; 16B-slot swizzle s = g ^ ((row>>1)&3)
// makes both DMA writes (contiguous) and frag ds_read_b128 conflict-free.
// EPI: 0=none 1=+res 2=gelu. NGUARD: col<nvalid. OSPLIT: write bf16 hi/lo.
template <int EPI, bool NGUARD, bool OSPLIT>
__global__ __launch_bounds__(256, 2) void gemm_bf16x3(
    const ushort* __restrict__ Ah, const ushort* __restrict__ Al,
    const ushort* __restrict__ Bh, const ushort* __restrict__ Bl,
    const float* __restrict__ Res, float* __restrict__ C,
    ushort* __restrict__ Oh, ushort* __restrict__ Ol,
    int K, int ldc, int nvalid) {
  __shared__ ushort S[2][4][128][32];  // [buf][plane: Ah,Al,Bh,Bl][row][k]
  const int tid = threadIdx.x;
  int bx = blockIdx.x, by = blockIdx.y;
  xcd_swizzle(gridDim.x, gridDim.y, bx, by);
  const int m0 = by * 128;
  const int n0 = bx * 128;
  const int lane = tid & 63;
  const int wid = tid >> 6;
  const int wr = wid >> 1, wc = wid & 1;  // wave 2x2 grid of 64x64
  const int fr = lane & 15, fq = lane >> 4;

  // staging geometry: wave `wid` owns plane `wid`; issue i covers rows
  // i*16..i*16+15; lane l -> physical (row = i*16 + (l>>2), slot = l&3),
  // fetching global k-group g = slot ^ ((row>>1)&3)  (XOR involution).
  const ushort* gplane = (wid == 0) ? Ah : (wid == 1) ? Al : (wid == 2) ? Bh : Bl;
  const int t0 = (wid < 2) ? m0 : n0;
  const int srow = lane >> 2;
  const int sslot = lane & 3;

  floatx4 acc[4][4] = {};

  auto stage = [&](int buf, int kk) {
#pragma unroll
    for (int i = 0; i < 8; i++) {
      int r = i * 16 + srow;
      int g = sslot ^ ((r >> 1) & 3);
      const ushort* gp = gplane + (size_t)(t0 + r) * K + kk + g * 8;
      gload_lds16((const void*)gp, (void*)&S[buf][wid][i * 16][0]);
    }
  };

  stage(0, 0);
  int cur = 0;
  for (int k0 = 0; k0 < K; k0 += 32) {
    // drains vmcnt (DMA into buf[cur] done) + lgkm (prev reads done)
    __syncthreads();
    if (k0 + 32 < K) stage(cur ^ 1, k0 + 32);  // next tile in flight over MFMA

    short8 fah[4], fal[4], fbh[4], fbl[4];
#pragma unroll
    for (int mi = 0; mi < 4; mi++) {
      int R = wr * 64 + mi * 16 + fr;
      int sw = (fq ^ ((R >> 1) & 3)) * 8;
      fah[mi] = *reinterpret_cast<const short8*>(&S[cur][0][R][sw]);
      fal[mi] = *reinterpret_cast<const short8*>(&S[cur][1][R][sw]);
    }
#pragma unroll
    for (int ni = 0; ni < 4; ni++) {
      int R = wc * 64 + ni * 16 + fr;
      int sw = (fq ^ ((R >> 1) & 3)) * 8;
      fbh[ni] = *reinterpret_cast<const short8*>(&S[cur][2][R][sw]);
      fbl[ni] = *reinterpret_cast<const short8*>(&S[cur][3][R][sw]);
    }
#pragma unroll
    for (int mi = 0; mi < 4; mi++)
#pragma unroll
      for (int ni = 0; ni < 4; ni++) {
        acc[mi][ni] = __builtin_amdgcn_mfma_f32_16x16x32_bf16(fah[mi], fbh[ni], acc[mi][ni], 0, 0, 0);
        acc[mi][ni] = __builtin_amdgcn_mfma_f32_16x16x32_bf16(fah[mi], fbl[ni], acc[mi][ni], 0, 0, 0);
        acc[mi][ni] = __builtin_amdgcn_mfma_f32_16x16x32_bf16(fal[mi], fbh[ni], acc[mi][ni], 0, 0, 0);
      }
    cur ^= 1;
  }

#pragma unroll
  for (int mi = 0; mi < 4; mi++) {
#pragma unroll
    for (int ni = 0; ni < 4; ni++) {
      int col = n0 + wc * 64 + ni * 16 + fr;
      if (!NGUARD || col < nvalid) {
#pragma unroll
        for (int j = 0; j < 4; j++) {
          int row = m0 + wr * 64 + mi * 16 + fq * 4 + j;
          float v = acc[mi][ni][j];
          if (EPI == 1) v += Res[(size_t)row * ldc + col];
          if (EPI == 2) v = 0.5f * v * (1.0f + erff(v * 0.70710678118654752f));
          if (OSPLIT) {
            ushort hi = f2bf(v);
            ushort lo = f2bf(v - bf2f(hi));
            Oh[(size_t)row * ldc + col] = hi;
            Ol[(size_t)row * ldc + col] = lo;
          } else {
            C[(size_t)row * ldc + col] = v;
          }
        }
      }
    }
  }
}

// ---------------------------------------------------------------- attention
// 4 lanes per q-row: lane-chunk c = tid&3 owns d in [c*16, c*16+16).
// Block = 256 threads = 64 q rows; grid (T/64, B*H) = (32, 24) = 768 blocks
// -> 3072 waves (3/SIMD) vs R7's 768 (occupancy fix). QK dot completed by
// 2-step __shfl_xor within the 4-lane group (bitwise-identical across lanes
// -> m/l softmax state stays consistent, no cross-lane combine needed).
// 32x64 K/V tiles in LDS; defer-rescale + whole-masked-tile skip.
// Output written directly as bf16 hi/lo planes (feeds proj GEMM A-operand).
__global__ __launch_bounds__(256) void attn_kernel(const float* __restrict__ qkv,
                                                   ushort* __restrict__ yh,
                                                   ushort* __restrict__ yl) {
  __shared__ float Ks[32][64];
  __shared__ float Vs[32][64];
  const int tid = threadIdx.x;
  const int bh = blockIdx.y;
  const int b = bh / HH, h = bh % HH;
  const int q0 = blockIdx.x * 64;
  const int qi = q0 + (tid >> 2);
  const int c = tid & 3;  // d-chunk
  const float* qptr = qkv + ((size_t)(b * TT + qi)) * (3 * CC) + h * HD + c * 16;
  float q[16], o[16];
#pragma unroll
  for (int i = 0; i < 4; i++) {
    float4 t = *(const float4*)(qptr + i * 4);
    q[i * 4] = t.x; q[i * 4 + 1] = t.y; q[i * 4 + 2] = t.z; q[i * 4 + 3] = t.w;
  }
#pragma unroll
  for (int i = 0; i < 16; i++) o[i] = 0.f;
  float m = -INFINITY, l = 0.f;

  const int kr = tid >> 3;       // staging tile row 0..31
  const int kc = (tid & 7) * 8;  // staging col base
  const size_t kbase = ((size_t)b * TT) * (3 * CC) + CC + h * HD;
  const size_t vbase = kbase + CC;

  for (int ks = 0; ks <= q0 + 63; ks += 32) {
    {
      const float* kp = qkv + kbase + (size_t)(ks + kr) * (3 * CC) + kc;
      float4 t0 = *(const float4*)(kp);
      float4 t1 = *(const float4*)(kp + 4);
      *(float4*)&Ks[kr][kc] = t0;
      *(float4*)&Ks[kr][kc + 4] = t1;
      const float* vp = qkv + vbase + (size_t)(ks + kr) * (3 * CC) + kc;
      float4 t2 = *(const float4*)(vp);
      float4 t3 = *(const float4*)(vp + 4);
      *(float4*)&Vs[kr][kc] = t2;
      *(float4*)&Vs[kr][kc + 4] = t3;
    }
    __syncthreads();
    float s[32];
    float tmax = -INFINITY;
#pragma unroll
    for (int j = 0; j < 32; j++) {
      float acc = 0.f;
#pragma unroll
      for (int d = 0; d < 16; d += 4) {
        float4 kv = *(const float4*)&Ks[j][c * 16 + d];
        acc = fmaf(q[d + 0], kv.x, acc);
        acc = fmaf(q[d + 1], kv.y, acc);
        acc = fmaf(q[d + 2], kv.z, acc);
        acc = fmaf(q[d + 3], kv.w, acc);
      }
      // complete the 64-d dot across the 4-lane group (commutative adds ->
      // bitwise-identical result in all 4 lanes)
      acc += __shfl_xor(acc, 1);
      acc += __shfl_xor(acc, 2);
      acc *= 0.125f; // 1/sqrt(64)
      if (ks + j > qi) acc = -INFINITY;
      s[j] = acc;
      tmax = fmaxf(tmax, acc);
    }
    if (tmax != -INFINITY) {  // tile has >=1 valid key for this row
      if (tmax > m) {         // running max grew (always true on first tile)
        float f = __expf(m - tmax);  // exp(-inf)=0 on first tile
        l *= f;
#pragma unroll
        for (int d = 0; d < 16; d++) o[d] *= f;
        m = tmax;
      }
      float ps = 0.f;
#pragma unroll
      for (int j = 0; j < 32; j++) {
        float p = __expf(s[j] - m);
        s[j] = p;
        ps += p;
      }
      l += ps;
#pragma unroll
      for (int j = 0; j < 32; j++) {
        float p = s[j];
#pragma unroll
        for (int d = 0; d < 16; d += 4) {
          float4 vv = *(const float4*)&Vs[j][c * 16 + d];
          o[d + 0] = fmaf(p, vv.x, o[d + 0]);
          o[d + 1] = fmaf(p, vv.y, o[d + 1]);
          o[d + 2] = fmaf(p, vv.z, o[d + 2]);
          o[d + 3] = fmaf(p, vv.w, o[d + 3]);
        }
      }
    }
    __syncthreads();
  }
  float inv = 1.0f / l;
  size_t yoff = ((size_t)(b * TT + qi)) * CC + h * HD + c * 16;
#pragma unroll
  for (int d = 0; d < 16; d += 4) {
    ushort4 hv, lv;
    float r0 = o[d + 0] * inv, r1 = o[d + 1] * inv;
    float r2 = o[d + 2] * inv, r3 = o[d + 3] * inv;
    hv.x = f2bf(r0); lv.x = f2bf(r0 - bf2f(hv.x));
    hv.y = f2bf(r1); lv.y = f2bf(r1 - bf2f(hv.y));
    hv.z = f2bf(r2); lv.z = f2bf(r2 - bf2f(hv.z));
    hv.w = f2bf(r3); lv.w = f2bf(r3 - bf2f(hv.w));
    *(ushort4*)(yh + yoff + d) = hv;
    *(ushort4*)(yl + yoff + d) = lv;
  }
}

// ------------------------------------------------- loss (single-pass online)
__global__ void loss_rows_kernel(const float* __restrict__ logits,
                                 const int* __restrict__ tgt,
                                 float* __restrict__ rloss) {
  __shared__ float redm[4], reds[4];
  const int row = blockIdx.x;
  const int tid = threadIdx.x;
  const int wid = tid >> 6, lane = tid & 63;
  const float* lr = logits + (size_t)row * VV;
  float m = -INFINITY, s = 0.f;
  // 12564 float4 groups cover elements [0, 50256); element 50256 is the tail.
  for (int i = tid; i < 12564; i += 256) {
    float4 v = *(const float4*)(lr + 4 * i);
    float mv = fmaxf(fmaxf(v.x, v.y), fmaxf(v.z, v.w));
    float mn = fmaxf(m, mv);
    s = s * __expf(m - mn) + __expf(v.x - mn) + __expf(v.y - mn) +
        __expf(v.z - mn) + __expf(v.w - mn);
    m = mn;
  }
  if (tid == 0) {
    float v = lr[VV - 1];
    float mn = fmaxf(m, v);
    s = s * __expf(m - mn) + __expf(v - mn);
    m = mn;
  }
#pragma unroll
  for (int o = 32; o > 0; o >>= 1) {
    float mo = __shfl_xor(m, o), so = __shfl_xor(s, o);
    float mn = fmaxf(m, mo);
    s = s * __expf(m - mn) + so * __expf(mo - mn);
    m = mn;
  }
  if (lane == 0) { redm[wid] = m; reds[wid] = s; }
  __syncthreads();
  if (tid == 0) {
    float M = redm[0], S = reds[0];
#pragma unroll
    for (int w = 1; w < 4; w++) {
      float mn = fmaxf(M, redm[w]);
      S = S * __expf(M - mn) + reds[w] * __expf(redm[w] - mn);
      M = mn;
    }
    float lt = lr[tgt[row]];
    rloss[row] = -(lt - M - logf(S));
  }
}

__global__ void loss_final_kernel(const float* __restrict__ rloss,
                                  float* __restrict__ out) {
  __shared__ float red[4];
  const int tid = threadIdx.x;
  const int wid = tid >> 6, lane = tid & 63;
  float s = 0.f;
  for (int i = tid; i < ROWS; i += 256) s += rloss[i];
#pragma unroll
  for (int o = 32; o > 0; o >>= 1) s += __shfl_xor(s, o);
  if (lane == 0) red[wid] = s;
  __syncthreads();
  if (tid == 0) out[0] = (red[0] + red[1] + red[2] + red[3]) * (1.0f / ROWS);
}

// ---------------------------------------------------------------- launch
extern "C" void kernel_launch(void* const* d_in, const int* in_sizes, int n_in,
                              void* d_out, int out_size, void* d_ws, size_t ws_size,
                              hipStream_t stream) {
  const int* idx = (const int*)d_in[0];
  const int* tgt = (const int*)d_in[1];
  const float* wte = (const float*)d_in[2];
  const float* wpe = (const float*)d_in[3];
  const float* ln1w = (const float*)d_in[4];
  const float* attnw = (const float*)d_in[5];
  const float* attnpw = (const float*)d_in[6];
  const float* ln2w = (const float*)d_in[7];
  const float* fcw = (const float*)d_in[8];
  const float* mlppw = (const float*)d_in[9];
  const float* lnfw = (const float*)d_in[10];
  const float* lmw = (const float*)d_in[11];

  float* logits = (float*)d_out;
  float* loss = logits + (size_t)ROWS * VV;

  // ---- workspace carve-up (~139 MB) ----
  float* x = (float*)d_ws;                        // [4096][768] fp32 residual
  float* qkvb = x + (size_t)ROWS * CC;            // [4096][2304] fp32
  float* rls = qkvb + (size_t)ROWS * 3 * CC;      // [4096]
  ushort* h_hi = (ushort*)(rls + ROWS);           // [4096][768] bf16 (ln out / attn out)
  ushort* h_lo = h_hi + (size_t)ROWS * CC;
  ushort* fA_hi = h_lo + (size_t)ROWS * CC;       // [4096][3072] bf16 (fc out)
  ushort* fA_lo = fA_hi + (size_t)ROWS * 4 * CC;
  ushort* wb_hi = fA_lo + (size_t)ROWS * 4 * CC;  // weight-T planes [8192][768] max
  ushort* wb_lo = wb_hi + (size_t)LMSTRIP * CC;

  embed_kernel<<<ROWS * CC / 4 / 256, 256, 0, stream>>>(idx, wte, wpe, x);

  for (int l = 0; l < 4; l++) {
    // --- attention half ---
    ln_split_kernel<<<ROWS / 4, 256, 0, stream>>>(x, ln1w + (size_t)l * CC, h_hi, h_lo);
    convt_kernel<<<dim3(3 * CC / 32, CC / 32), 256, 0, stream>>>(
        attnw + (size_t)l * CC * 3 * CC, CC, 3 * CC, 0, wb_hi, wb_lo);
    gemm_bf16x3<0, false, false><<<dim3(3 * CC / 128, ROWS / 128), 256, 0, stream>>>(
        h_hi, h_lo, wb_hi, wb_lo, nullptr, qkvb, nullptr, nullptr, CC, 3 * CC, 3 * CC);
    attn_kernel<<<dim3(TT / 64, BBATCH * HH), 256, 0, stream>>>(qkvb, h_hi, h_lo);
    convt_kernel<<<dim3(CC / 32, CC / 32), 256, 0, stream>>>(
        attnpw + (size_t)l * CC * CC, CC, CC, 0, wb_hi, wb_lo);
    gemm_bf16x3<1, false, false><<<dim3(CC / 128, ROWS / 128), 256, 0, stream>>>(
        h_hi, h_lo, wb_hi, wb_lo, x, x, nullptr, nullptr, CC, CC, CC);
    // --- MLP half ---
    ln_split_kernel<<<ROWS / 4, 256, 0, stream>>>(x, ln2w + (size_t)l * CC, h_hi, h_lo);
    convt_kernel<<<dim3(4 * CC / 32, CC / 32), 256, 0, stream>>>(
        fcw + (size_t)l * CC * 4 * CC, CC, 4 * CC, 0, wb_hi, wb_lo);
    gemm_bf16x3<2, false, true><<<dim3(4 * CC / 128, ROWS / 128), 256, 0, stream>>>(
        h_hi, h_lo, wb_hi, wb_lo, nullptr, nullptr, fA_hi, fA_lo, CC, 4 * CC, 4 * CC);
    convt_kernel<<<dim3(CC / 32, 4 * CC / 32), 256, 0, stream>>>(
        mlppw + (size_t)l * 4 * CC * CC, 4 * CC, CC, 0, wb_hi, wb_lo);
    gemm_bf16x3<1, false, false><<<dim3(CC / 128, ROWS / 128), 256, 0, stream>>>(
        fA_hi, fA_lo, wb_hi, wb_lo, x, x, nullptr, nullptr, 4 * CC, CC, CC);
  }

  ln_split_kernel<<<ROWS / 4, 256, 0, stream>>>(x, lnfw, h_hi, h_lo);

  // lm_head in column strips of 8192 through the weight-T buffer
  for (int c0 = 0; c0 < VV; c0 += LMSTRIP) {
    int nt = VV - c0 < LMSTRIP ? VV - c0 : LMSTRIP;
    convt_kernel<<<dim3(LMSTRIP / 32, CC / 32), 256, 0, stream>>>(
        lmw, CC, VV, c0, wb_hi, wb_lo);
    if (nt == LMSTRIP) {
      gemm_bf16x3<0, false, false><<<dim3(LMSTRIP / 128, ROWS / 128), 256, 0, stream>>>(
          h_hi, h_lo, wb_hi, wb_lo, nullptr, logits + c0, nullptr, nullptr, CC, VV, nt);
    } else {
      gemm_bf16x3<0, true, false><<<dim3((nt + 127) / 128, ROWS / 128), 256, 0, stream>>>(
          h_hi, h_lo, wb_hi, wb_lo, nullptr, logits + c0, nullptr, nullptr, CC, VV, nt);
    }
  }

  loss_rows_kernel<<<ROWS, 256, 0, stream>>>(logits, tgt, rls);
  loss_final_kernel<<<1, 256, 0, stream>>>(rls, loss);
}

// Round 9
// 5629.094 us; speedup vs baseline: 1.3072x; 1.0137x over previous
//
#include <hip/hip_runtime.h>
#include <math.h>

// GPT forward: B=2, T=2048, C=768, H=12, hd=64, L=4, V=50257
// out = logits[B*T*V] (fp32) then loss[1] (fp32), concatenated.
// GEMMs run as bf16x3 split-MFMA (error ~2^-16 per product, fp32-equivalent).
// Staging via global_load_lds (16B) into XOR-swizzled linear LDS (rule #21).
// Attention: 4 lanes per q-row + register-prefetched K/V staging (T14).

#define TT 2048
#define CC 768
#define HH 12
#define HD 64
#define VV 50257
#define BBATCH 2
#define ROWS (BBATCH * TT) /* 4096 */
#define LMSTRIP 8192

typedef __attribute__((ext_vector_type(8))) short short8;   // 8 bf16 (4 VGPR)
typedef __attribute__((ext_vector_type(4))) float floatx4;  // MFMA acc

// address-space-qualified pointer types for the global_load_lds builtin
typedef const void __attribute__((address_space(1)))* gas1_cvp;
typedef void __attribute__((address_space(3)))* as3_vp;

static __device__ __forceinline__ void gload_lds16(const void* g, void* l) {
  __builtin_amdgcn_global_load_lds(
      (gas1_cvp)(unsigned long long)g,
      (as3_vp)(unsigned int)(unsigned long long)l, 16, 0, 0);
}

static __device__ __forceinline__ ushort f2bf(float x) {
  unsigned u = __float_as_uint(x);
  unsigned r = (u + 0x7fff + ((u >> 16) & 1)) >> 16;  // round-nearest-even
  return (ushort)r;
}
static __device__ __forceinline__ float bf2f(ushort h) {
  return __uint_as_float(((unsigned)h) << 16);
}

// Bijective XCD-aware remap (m204).
static __device__ __forceinline__ void xcd_swizzle(int gx, int gy, int& bx, int& by) {
  int nwg = gx * gy;
  int orig = by * gx + bx;
  int q = nwg >> 3, r = nwg & 7;
  int xcd = orig & 7, local = orig >> 3;
  int wgid = (xcd < r ? xcd * (q + 1) : r * (q + 1) + (xcd - r) * q) + local;
  bx = wgid % gx;
  by = wgid / gx;
}

// ---------------------------------------------------------------- embedding
__global__ void embed_kernel(const int* __restrict__ idx,
                             const float* __restrict__ wte,
                             const float* __restrict__ wpe,
                             float* __restrict__ x) {
  int i = blockIdx.x * blockDim.x + threadIdx.x; // float4 index
  int row = i / (CC / 4);
  int c4 = (i % (CC / 4)) * 4;
  int t = row % TT;
  int tok = idx[row];
  float4 a = *(const float4*)(wte + (size_t)tok * CC + c4);
  float4 p = *(const float4*)(wpe + (size_t)t * CC + c4);
  float4 o;
  o.x = a.x + p.x; o.y = a.y + p.y; o.z = a.z + p.z; o.w = a.w + p.w;
  *(float4*)(x + (size_t)row * CC + c4) = o;
}

// ------------------------------------------------- layernorm -> bf16 hi/lo
__global__ void ln_split_kernel(const float* __restrict__ x,
                                const float* __restrict__ w,
                                ushort* __restrict__ hhi,
                                ushort* __restrict__ hlo) {
  int wid = threadIdx.x >> 6;
  int lane = threadIdx.x & 63;
  int row = blockIdx.x * 4 + wid;
  const float* xr = x + (size_t)row * CC;
  float v[12];
#pragma unroll
  for (int c = 0; c < 3; c++) {
    float4 t = *(const float4*)(xr + c * 256 + lane * 4);
    v[c * 4 + 0] = t.x; v[c * 4 + 1] = t.y; v[c * 4 + 2] = t.z; v[c * 4 + 3] = t.w;
  }
  float s = 0.f;
#pragma unroll
  for (int i = 0; i < 12; i++) s += v[i];
#pragma unroll
  for (int o = 32; o > 0; o >>= 1) s += __shfl_xor(s, o);
  float mean = s * (1.0f / CC);
  float vs = 0.f;
#pragma unroll
  for (int i = 0; i < 12; i++) { float d = v[i] - mean; vs += d * d; }
#pragma unroll
  for (int o = 32; o > 0; o >>= 1) vs += __shfl_xor(vs, o);
  float rs = rsqrtf(vs * (1.0f / CC) + 1e-5f);
#pragma unroll
  for (int c = 0; c < 3; c++) {
    float4 wv = *(const float4*)(w + c * 256 + lane * 4);
    float r[4];
    r[0] = (v[c * 4 + 0] - mean) * rs * wv.x;
    r[1] = (v[c * 4 + 1] - mean) * rs * wv.y;
    r[2] = (v[c * 4 + 2] - mean) * rs * wv.z;
    r[3] = (v[c * 4 + 3] - mean) * rs * wv.w;
    ushort4 h, l;
    h.x = f2bf(r[0]); l.x = f2bf(r[0] - bf2f(h.x));
    h.y = f2bf(r[1]); l.y = f2bf(r[1] - bf2f(h.y));
    h.z = f2bf(r[2]); l.z = f2bf(r[2] - bf2f(h.z));
    h.w = f2bf(r[3]); l.w = f2bf(r[3] - bf2f(h.w));
    size_t ob = (size_t)row * CC + c * 256 + lane * 4;
    *(ushort4*)(hhi + ob) = h;
    *(ushort4*)(hlo + ob) = l;
  }
}

// --------------------------------------- weight transpose + bf16 hi/lo split
__global__ void convt_kernel(const float* __restrict__ in, int Ktot, int Ntot,
                             int c0, ushort* __restrict__ oh,
                             ushort* __restrict__ ol) {
  __shared__ float T[32][33];
  const int n0 = blockIdx.x * 32, k0 = blockIdx.y * 32;
  const int tid = threadIdx.x;
  {
    const int kr = tid >> 3, nc = (tid & 7) * 4;
#pragma unroll
    for (int i = 0; i < 4; i++) {
      int gc = c0 + n0 + nc + i;
      float v = 0.f;
      if (gc < Ntot) v = in[(size_t)(k0 + kr) * Ntot + gc];
      T[kr][nc + i] = v;
    }
  }
  __syncthreads();
  const int nr = tid >> 3, kc = (tid & 7) * 4;
  ushort4 h, l;
  float v0 = T[kc + 0][nr], v1 = T[kc + 1][nr], v2 = T[kc + 2][nr], v3 = T[kc + 3][nr];
  h.x = f2bf(v0); l.x = f2bf(v0 - bf2f(h.x));
  h.y = f2bf(v1); l.y = f2bf(v1 - bf2f(h.y));
  h.z = f2bf(v2); l.z = f2bf(v2 - bf2f(h.z));
  h.w = f2bf(v3); l.w = f2bf(v3 - bf2f(h.w));
  size_t ob = (size_t)(n0 + nr) * Ktot + k0 + kc;
  *(ushort4*)(oh + ob) = h;
  *(ushort4*)(ol + ob) = l;
}

// ------------------------------------------------------------ bf16x3 GEMM
// 128x128 tile, BK=32, 4 waves, 64x64 per wave. global_load_lds staging,
// double-buffered. MFMA issued as 3 passes of 16 independent ops (ILP:
// no back-to-back dependent MFMAs on the same acc).
template <int EPI, bool NGUARD, bool OSPLIT>
__global__ __launch_bounds__(256, 2) void gemm_bf16x3(
    const ushort* __restrict__ Ah, const ushort* __restrict__ Al,
    const ushort* __restrict__ Bh, const ushort* __restrict__ Bl,
    const float* __restrict__ Res, float* __restrict__ C,
    ushort* __restrict__ Oh, ushort* __restrict__ Ol,
    int K, int ldc, int nvalid) {
  __shared__ ushort S[2][4][128][32];  // [buf][plane: Ah,Al,Bh,Bl][row][k]
  const int tid = threadIdx.x;
  int bx = blockIdx.x, by = blockIdx.y;
  xcd_swizzle(gridDim.x, gridDim.y, bx, by);
  const int m0 = by * 128;
  const int n0 = bx * 128;
  const int lane = tid & 63;
  const int wid = tid >> 6;
  const int wr = wid >> 1, wc = wid & 1;  // wave 2x2 grid of 64x64
  const int fr = lane & 15, fq = lane >> 4;

  const ushort* gplane = (wid == 0) ? Ah : (wid == 1) ? Al : (wid == 2) ? Bh : Bl;
  const int t0 = (wid < 2) ? m0 : n0;
  const int srow = lane >> 2;
  const int sslot = lane & 3;

  floatx4 acc[4][4] = {};

  auto stage = [&](int buf, int kk) {
#pragma unroll
    for (int i = 0; i < 8; i++) {
      int r = i * 16 + srow;
      int g = sslot ^ ((r >> 1) & 3);
      const ushort* gp = gplane + (size_t)(t0 + r) * K + kk + g * 8;
      gload_lds16((const void*)gp, (void*)&S[buf][wid][i * 16][0]);
    }
  };

  stage(0, 0);
  int cur = 0;
  for (int k0 = 0; k0 < K; k0 += 32) {
    __syncthreads();
    if (k0 + 32 < K) stage(cur ^ 1, k0 + 32);

    short8 fah[4], fal[4], fbh[4], fbl[4];
#pragma unroll
    for (int mi = 0; mi < 4; mi++) {
      int R = wr * 64 + mi * 16 + fr;
      int sw = (fq ^ ((R >> 1) & 3)) * 8;
      fah[mi] = *reinterpret_cast<const short8*>(&S[cur][0][R][sw]);
      fal[mi] = *reinterpret_cast<const short8*>(&S[cur][1][R][sw]);
    }
#pragma unroll
    for (int ni = 0; ni < 4; ni++) {
      int R = wc * 64 + ni * 16 + fr;
      int sw = (fq ^ ((R >> 1) & 3)) * 8;
      fbh[ni] = *reinterpret_cast<const short8*>(&S[cur][2][R][sw]);
      fbl[ni] = *reinterpret_cast<const short8*>(&S[cur][3][R][sw]);
    }
    // three passes of 16 independent MFMAs each
#pragma unroll
    for (int mi = 0; mi < 4; mi++)
#pragma unroll
      for (int ni = 0; ni < 4; ni++)
        acc[mi][ni] = __builtin_amdgcn_mfma_f32_16x16x32_bf16(fah[mi], fbh[ni], acc[mi][ni], 0, 0, 0);
#pragma unroll
    for (int mi = 0; mi < 4; mi++)
#pragma unroll
      for (int ni = 0; ni < 4; ni++)
        acc[mi][ni] = __builtin_amdgcn_mfma_f32_16x16x32_bf16(fah[mi], fbl[ni], acc[mi][ni], 0, 0, 0);
#pragma unroll
    for (int mi = 0; mi < 4; mi++)
#pragma unroll
      for (int ni = 0; ni < 4; ni++)
        acc[mi][ni] = __builtin_amdgcn_mfma_f32_16x16x32_bf16(fal[mi], fbh[ni], acc[mi][ni], 0, 0, 0);
    cur ^= 1;
  }

#pragma unroll
  for (int mi = 0; mi < 4; mi++) {
#pragma unroll
    for (int ni = 0; ni < 4; ni++) {
      int col = n0 + wc * 64 + ni * 16 + fr;
      if (!NGUARD || col < nvalid) {
#pragma unroll
        for (int j = 0; j < 4; j++) {
          int row = m0 + wr * 64 + mi * 16 + fq * 4 + j;
          float v = acc[mi][ni][j];
          if (EPI == 1) v += Res[(size_t)row * ldc + col];
          if (EPI == 2) v = 0.5f * v * (1.0f + erff(v * 0.70710678118654752f));
          if (OSPLIT) {
            ushort hi = f2bf(v);
            ushort lo = f2bf(v - bf2f(hi));
            Oh[(size_t)row * ldc + col] = hi;
            Ol[(size_t)row * ldc + col] = lo;
          } else {
            C[(size_t)row * ldc + col] = v;
          }
        }
      }
    }
  }
}

// ---------------------------------------------------------------- attention
// 4 lanes per q-row; 32x64 K/V tiles in LDS with register-prefetch (T14):
// next tile's 4 float4 loads issue before the compute phase, LDS write lands
// after the barrier -> HBM latency hides under QK/PV. Long blocks (high q0)
// launch first via bx reversal (causal imbalance tail).
__global__ __launch_bounds__(256) void attn_kernel(const float* __restrict__ qkv,
                                                   ushort* __restrict__ yh,
                                                   ushort* __restrict__ yl) {
  __shared__ float Ks[32][64];
  __shared__ float Vs[32][64];
  const int tid = threadIdx.x;
  const int bh = blockIdx.y;
  const int b = bh / HH, h = bh % HH;
  const int q0 = (gridDim.x - 1 - blockIdx.x) * 64;  // long blocks first
  const int qi = q0 + (tid >> 2);
  const int c = tid & 3;  // d-chunk
  const float* qptr = qkv + ((size_t)(b * TT + qi)) * (3 * CC) + h * HD + c * 16;
  float q[16], o[16];
#pragma unroll
  for (int i = 0; i < 4; i++) {
    float4 t = *(const float4*)(qptr + i * 4);
    q[i * 4] = t.x; q[i * 4 + 1] = t.y; q[i * 4 + 2] = t.z; q[i * 4 + 3] = t.w;
  }
#pragma unroll
  for (int i = 0; i < 16; i++) o[i] = 0.f;
  float m = -INFINITY, l = 0.f;

  const int kr = tid >> 3;       // staging tile row 0..31
  const int kc = (tid & 7) * 8;  // staging col base
  const size_t kbase = ((size_t)b * TT) * (3 * CC) + CC + h * HD;
  const size_t vbase = kbase + CC;

  float4 pk0, pk1, pv0, pv1;  // prefetch regs
  auto ldkv = [&](int ks) {
    int row = ks + kr;
    if (row > TT - 1) row = TT - 1;  // clamp; values unused on last iter
    const float* kp = qkv + kbase + (size_t)row * (3 * CC) + kc;
    pk0 = *(const float4*)(kp);
    pk1 = *(const float4*)(kp + 4);
    const float* vp = qkv + vbase + (size_t)row * (3 * CC) + kc;
    pv0 = *(const float4*)(vp);
    pv1 = *(const float4*)(vp + 4);
  };
  ldkv(0);

  for (int ks = 0; ks <= q0 + 63; ks += 32) {
    __syncthreads();  // prev compute's LDS reads retired
    *(float4*)&Ks[kr][kc] = pk0;
    *(float4*)&Ks[kr][kc + 4] = pk1;
    *(float4*)&Vs[kr][kc] = pv0;
    *(float4*)&Vs[kr][kc + 4] = pv1;
    if (ks + 32 <= q0 + 63) ldkv(ks + 32);  // in flight over this compute
    __syncthreads();

    float s[32];
    float tmax = -INFINITY;
#pragma unroll
    for (int j = 0; j < 32; j++) {
      float acc = 0.f;
#pragma unroll
      for (int d = 0; d < 16; d += 4) {
        float4 kv = *(const float4*)&Ks[j][c * 16 + d];
        acc = fmaf(q[d + 0], kv.x, acc);
        acc = fmaf(q[d + 1], kv.y, acc);
        acc = fmaf(q[d + 2], kv.z, acc);
        acc = fmaf(q[d + 3], kv.w, acc);
      }
      // complete 64-d dot across the 4-lane group (identical in all 4 lanes)
      acc += __shfl_xor(acc, 1);
      acc += __shfl_xor(acc, 2);
      acc *= 0.125f; // 1/sqrt(64)
      if (ks + j > qi) acc = -INFINITY;
      s[j] = acc;
      tmax = fmaxf(tmax, acc);
    }
    if (tmax != -INFINITY) {  // tile has >=1 valid key for this row
      if (tmax > m) {         // defer-rescale
        float f = __expf(m - tmax);  // exp(-inf)=0 on first tile
        l *= f;
#pragma unroll
        for (int d = 0; d < 16; d++) o[d] *= f;
        m = tmax;
      }
      float ps = 0.f;
#pragma unroll
      for (int j = 0; j < 32; j++) {
        float p = __expf(s[j] - m);
        s[j] = p;
        ps += p;
      }
      l += ps;
#pragma unroll
      for (int j = 0; j < 32; j++) {
        float p = s[j];
#pragma unroll
        for (int d = 0; d < 16; d += 4) {
          float4 vv = *(const float4*)&Vs[j][c * 16 + d];
          o[d + 0] = fmaf(p, vv.x, o[d + 0]);
          o[d + 1] = fmaf(p, vv.y, o[d + 1]);
          o[d + 2] = fmaf(p, vv.z, o[d + 2]);
          o[d + 3] = fmaf(p, vv.w, o[d + 3]);
        }
      }
    }
  }
  float inv = 1.0f / l;
  size_t yoff = ((size_t)(b * TT + qi)) * CC + h * HD + c * 16;
#pragma unroll
  for (int d = 0; d < 16; d += 4) {
    ushort4 hv, lv;
    float r0 = o[d + 0] * inv, r1 = o[d + 1] * inv;
    float r2 = o[d + 2] * inv, r3 = o[d + 3] * inv;
    hv.x = f2bf(r0); lv.x = f2bf(r0 - bf2f(hv.x));
    hv.y = f2bf(r1); lv.y = f2bf(r1 - bf2f(hv.y));
    hv.z = f2bf(r2); lv.z = f2bf(r2 - bf2f(hv.z));
    hv.w = f2bf(r3); lv.w = f2bf(r3 - bf2f(hv.w));
    *(ushort4*)(yh + yoff + d) = hv;
    *(ushort4*)(yl + yoff + d) = lv;
  }
}

// ------------------------------------------------- loss (single-pass online)
__global__ void loss_rows_kernel(const float* __restrict__ logits,
                                 const int* __restrict__ tgt,
                                 float* __restrict__ rloss) {
  __shared__ float redm[4], reds[4];
  const int row = blockIdx.x;
  const int tid = threadIdx.x;
  const int wid = tid >> 6, lane = tid & 63;
  const float* lr = logits + (size_t)row * VV;
  float m = -INFINITY, s = 0.f;
  for (int i = tid; i < 12564; i += 256) {
    float4 v = *(const float4*)(lr + 4 * i);
    float mv = fmaxf(fmaxf(v.x, v.y), fmaxf(v.z, v.w));
    float mn = fmaxf(m, mv);
    s = s * __expf(m - mn) + __expf(v.x - mn) + __expf(v.y - mn) +
        __expf(v.z - mn) + __expf(v.w - mn);
    m = mn;
  }
  if (tid == 0) {
    float v = lr[VV - 1];
    float mn = fmaxf(m, v);
    s = s * __expf(m - mn) + __expf(v - mn);
    m = mn;
  }
#pragma unroll
  for (int o = 32; o > 0; o >>= 1) {
    float mo = __shfl_xor(m, o), so = __shfl_xor(s, o);
    float mn = fmaxf(m, mo);
    s = s * __expf(m - mn) + so * __expf(mo - mn);
    m = mn;
  }
  if (lane == 0) { redm[wid] = m; reds[wid] = s; }
  __syncthreads();
  if (tid == 0) {
    float M = redm[0], S = reds[0];
#pragma unroll
    for (int w = 1; w < 4; w++) {
      float mn = fmaxf(M, redm[w]);
      S = S * __expf(M - mn) + reds[w] * __expf(redm[w] - mn);
      M = mn;
    }
    float lt = lr[tgt[row]];
    rloss[row] = -(lt - M - logf(S));
  }
}

__global__ void loss_final_kernel(const float* __restrict__ rloss,
                                  float* __restrict__ out) {
  __shared__ float red[4];
  const int tid = threadIdx.x;
  const int wid = tid >> 6, lane = tid & 63;
  float s = 0.f;
  for (int i = tid; i < ROWS; i += 256) s += rloss[i];
#pragma unroll
  for (int o = 32; o > 0; o >>= 1) s += __shfl_xor(s, o);
  if (lane == 0) red[wid] = s;
  __syncthreads();
  if (tid == 0) out[0] = (red[0] + red[1] + red[2] + red[3]) * (1.0f / ROWS);
}

// ---------------------------------------------------------------- launch
extern "C" void kernel_launch(void* const* d_in, const int* in_sizes, int n_in,
                              void* d_out, int out_size, void* d_ws, size_t ws_size,
                              hipStream_t stream) {
  const int* idx = (const int*)d_in[0];
  const int* tgt = (const int*)d_in[1];
  const float* wte = (const float*)d_in[2];
  const float* wpe = (const float*)d_in[3];
  const float* ln1w = (const float*)d_in[4];
  const float* attnw = (const float*)d_in[5];
  const float* attnpw = (const float*)d_in[6];
  const float* ln2w = (const float*)d_in[7];
  const float* fcw = (const float*)d_in[8];
  const float* mlppw = (const float*)d_in[9];
  const float* lnfw = (const float*)d_in[10];
  const float* lmw = (const float*)d_in[11];

  float* logits = (float*)d_out;
  float* loss = logits + (size_t)ROWS * VV;

  // ---- workspace carve-up (~139 MB) ----
  float* x = (float*)d_ws;                        // [4096][768] fp32 residual
  float* qkvb = x + (size_t)ROWS * CC;            // [4096][2304] fp32
  float* rls = qkvb + (size_t)ROWS * 3 * CC;      // [4096]
  ushort* h_hi = (ushort*)(rls + ROWS);           // [4096][768] bf16
  ushort* h_lo = h_hi + (size_t)ROWS * CC;
  ushort* fA_hi = h_lo + (size_t)ROWS * CC;       // [4096][3072] bf16 (fc out)
  ushort* fA_lo = fA_hi + (size_t)ROWS * 4 * CC;
  ushort* wb_hi = fA_lo + (size_t)ROWS * 4 * CC;  // weight-T planes [8192][768] max
  ushort* wb_lo = wb_hi + (size_t)LMSTRIP * CC;

  embed_kernel<<<ROWS * CC / 4 / 256, 256, 0, stream>>>(idx, wte, wpe, x);

  for (int l = 0; l < 4; l++) {
    // --- attention half ---
    ln_split_kernel<<<ROWS / 4, 256, 0, stream>>>(x, ln1w + (size_t)l * CC, h_hi, h_lo);
    convt_kernel<<<dim3(3 * CC / 32, CC / 32), 256, 0, stream>>>(
        attnw + (size_t)l * CC * 3 * CC, CC, 3 * CC, 0, wb_hi, wb_lo);
    gemm_bf16x3<0, false, false><<<dim3(3 * CC / 128, ROWS / 128), 256, 0, stream>>>(
        h_hi, h_lo, wb_hi, wb_lo, nullptr, qkvb, nullptr, nullptr, CC, 3 * CC, 3 * CC);
    attn_kernel<<<dim3(TT / 64, BBATCH * HH), 256, 0, stream>>>(qkvb, h_hi, h_lo);
    convt_kernel<<<dim3(CC / 32, CC / 32), 256, 0, stream>>>(
        attnpw + (size_t)l * CC * CC, CC, CC, 0, wb_hi, wb_lo);
    gemm_bf16x3<1, false, false><<<dim3(CC / 128, ROWS / 128), 256, 0, stream>>>(
        h_hi, h_lo, wb_hi, wb_lo, x, x, nullptr, nullptr, CC, CC, CC);
    // --- MLP half ---
    ln_split_kernel<<<ROWS / 4, 256, 0, stream>>>(x, ln2w + (size_t)l * CC, h_hi, h_lo);
    convt_kernel<<<dim3(4 * CC / 32, CC / 32), 256, 0, stream>>>(
        fcw + (size_t)l * CC * 4 * CC, CC, 4 * CC, 0, wb_hi, wb_lo);
    gemm_bf16x3<2, false, true><<<dim3(4 * CC / 128, ROWS / 128), 256, 0, stream>>>(
        h_hi, h_lo, wb_hi, wb_lo, nullptr, nullptr, fA_hi, fA_lo, CC, 4 * CC, 4 * CC);
    convt_kernel<<<dim3(CC / 32, 4 * CC / 32), 256, 0, stream>>>(
        mlppw + (size_t)l * 4 * CC * CC, 4 * CC, CC, 0, wb_hi, wb_lo);
    gemm_bf16x3<1, false, false><<<dim3(CC / 128, ROWS / 128), 256, 0, stream>>>(
        fA_hi, fA_lo, wb_hi, wb_lo, x, x, nullptr, nullptr, 4 * CC, CC, CC);
  }

  ln_split_kernel<<<ROWS / 4, 256, 0, stream>>>(x, lnfw, h_hi, h_lo);

  // lm_head in column strips of 8192 through the weight-T buffer
  for (int c0 = 0; c0 < VV; c0 += LMSTRIP) {
    int nt = VV - c0 < LMSTRIP ? VV - c0 : LMSTRIP;
    convt_kernel<<<dim3(LMSTRIP / 32, CC / 32), 256, 0, stream>>>(
        lmw, CC, VV, c0, wb_hi, wb_lo);
    if (nt == LMSTRIP) {
      gemm_bf16x3<0, false, false><<<dim3(LMSTRIP / 128, ROWS / 128), 256, 0, stream>>>(
          h_hi, h_lo, wb_hi, wb_lo, nullptr, logits + c0, nullptr, nullptr, CC, VV, nt);
    } else {
      gemm_bf16x3<0, true, false><<<dim3((nt + 127) / 128, ROWS / 128), 256, 0, stream>>>(
          h_hi, h_lo, wb_hi, wb_lo, nullptr, logits + c0, nullptr, nullptr, CC, VV, nt);
    }
  }

  loss_rows_kernel<<<ROWS, 256, 0, stream>>>(logits, tgt, rls);
  loss_final_kernel<<<1, 256, 0, stream>>>(rls, loss);
}